// Round 11
// baseline (1941.342 us; speedup 1.0000x reference)
//
#include <hip/hip_runtime.h>
#include <hip/hip_fp16.h>

#define N_POINTS 2000000
#define NLEV 16
#define LOG2_T 19
#define T_MASK ((1u << LOG2_T) - 1u)
#define TF ((size_t)(1u << LOG2_T) * 2)   // floats per (part, level) slice

#define PTS_PER_BLK 256
#define CHUNKS ((N_POINTS + PTS_PER_BLK - 1) / PTS_PER_BLK)   // 7813
#define NCH4 ((N_POINTS + 1023) / 1024)                        // 1954 (4 pts/thread)

typedef float f32x2 __attribute__((ext_vector_type(2)));
typedef float f32x4 __attribute__((ext_vector_type(4)));
typedef unsigned u32;
typedef u32 u32x4 __attribute__((ext_vector_type(4)));

// floor(16 * 1.5^l) for l = 0..15 (double-precision derived, exact in fp32)
__constant__ float c_res[NLEV] = {
    16.f, 24.f, 36.f, 54.f, 81.f, 121.f, 182.f, 273.f,
    410.f, 615.f, 922.f, 1383.f, 2075.f, 3113.f, 4670.f, 7006.f
};

// ws: wsout @0 : u32[NLEV][N_POINTS]  (f16 pair per (l,n))  128 MB
// Handoff pattern: thread-indexed full-region NT-write -> NT-read (the ONLY
// pattern proven to work across dispatches in this harness: r0/r3 pass, every
// data-dependent-scatter variant r4-r10 failed). Do not reintroduce scatters.
#define WSOUT_F16_BYTES ((size_t)NLEV * N_POINTS * 4)

__device__ __forceinline__ int part_of(float cx, float cy, float cz) {
    int px = (int)floorf(cx * 2.0f); px = px < 0 ? 0 : (px > 1 ? 1 : px);
    int py = (int)floorf(cy * 2.0f); py = py < 0 ? 0 : (py > 1 ? 1 : py);
    int pz = (int)floorf(cz * 2.0f); pz = pz < 0 ? 0 : (pz > 1 ? 1 : pz);
    return px * 4 + py * 2 + pz;
}

__device__ __forceinline__ void enc_core(
        const float* __restrict__ tb, float res,
        float cx, float cy, float cz, float& s0, float& s1) {
    const float sx = cx * res, sy = cy * res, sz = cz * res;
    const float fx0 = floorf(sx), fy0 = floorf(sy), fz0 = floorf(sz);
    const float fx = sx - fx0, fy = sy - fy0, fz = sz - fz0;
    const uint32_t ix = (uint32_t)fx0, iy = (uint32_t)fy0, iz = (uint32_t)fz0;
    const uint32_t hx0 = ix, hx1 = ix + 1u;                  // PRIME0 == 1
    const uint32_t hy0 = iy * 2654435761u, hy1 = (iy + 1u) * 2654435761u;
    const uint32_t hz0 = iz * 805459861u,  hz1 = (iz + 1u) * 805459861u;
    const float gx = 1.0f - fx, gy = 1.0f - fy, gz = 1.0f - fz;
    s0 = 0.0f; s1 = 0.0f;
    #pragma unroll
    for (int c = 0; c < 8; ++c) {
        const uint32_t h = (((c & 1) ? hx1 : hx0)
                          ^ ((c & 2) ? hy1 : hy0)
                          ^ ((c & 4) ? hz1 : hz0)) & T_MASK;
        const f32x2 e = *(const f32x2*)(tb + (size_t)h * 2);
        float w = ((c & 1) ? fx : gx) * ((c & 2) ? fy : gy);
        w = w * ((c & 4) ? fz : gz);
        s0 += w * e.x;
        s1 += w * e.y;
    }
}

__device__ __forceinline__ u32 pack_f16(float s0, float s1) {
    return (u32)__half_as_ushort(__float2half(s0))
         | ((u32)__half_as_ushort(__float2half(s1)) << 16);
}

// ---- enc: level-major, 4 points/thread, f16-packed NT wsout ----------------
__global__ __launch_bounds__(256) void enc4_k(
        const float* __restrict__ coords,
        const float* __restrict__ tables,
        u32* __restrict__ wsout) {
    const int b = blockIdx.x;
    const int l = b / NCH4;                    // level = slowest digit
    const int chunk = b - l * NCH4;
    const int n = (chunk * 256 + threadIdx.x) * 4;   // 4 consecutive points
    if (n >= N_POINTS) return;                 // N % 4 == 0: all-or-nothing

    // 12 floats = 48 B, 16B-aligned (n % 4 == 0 -> 3n % 4 == 0)
    const f32x4 c0 = *(const f32x4*)(coords + (size_t)n * 3 + 0);
    const f32x4 c1 = *(const f32x4*)(coords + (size_t)n * 3 + 4);
    const f32x4 c2 = *(const f32x4*)(coords + (size_t)n * 3 + 8);
    const float X[4] = { c0.x, c0.w, c1.z, c2.y };
    const float Y[4] = { c0.y, c1.x, c1.w, c2.z };
    const float Z[4] = { c0.z, c1.y, c2.x, c2.w };

    const float res = c_res[l];
    u32x4 pk;
    #pragma unroll
    for (int k = 0; k < 4; ++k) {
        const int part = part_of(X[k], Y[k], Z[k]);
        const float* __restrict__ tb = tables + ((size_t)(part * NLEV + l)) * TF;
        float s0, s1;
        enc_core(tb, res, X[k], Y[k], Z[k], s0, s1);
        pk[k] = pack_f16(s0, s1);
    }

    // wsout[l][n..n+3] — 16 B aligned NT store, thread-indexed address
    __builtin_nontemporal_store(pk, (u32x4*)&wsout[(size_t)l * N_POINTS + n]);
}

// ---- transpose: wsout[l][n] (f16 pairs) -> out[n][l] (f32 pairs) -----------
__global__ __launch_bounds__(256) void transpose_f16_k(
        const u32* __restrict__ wsout, f32x2* __restrict__ out) {
    __shared__ u32 tile[NLEV][PTS_PER_BLK + 1];
    const int n0 = blockIdx.x * PTS_PER_BLK;
    const int t = threadIdx.x;

    #pragma unroll
    for (int l = 0; l < NLEV; ++l) {
        const int n = n0 + t;
        if (n < N_POINTS)
            tile[l][t] = __builtin_nontemporal_load(&wsout[(size_t)l * N_POINTS + n]);
    }
    __syncthreads();

    const int ll = t & 15;
    const int hi = t >> 4;
    #pragma unroll
    for (int j = 0; j < NLEV; ++j) {
        const int pp = j * 16 + hi;           // covers 0..255 across j
        const int n = n0 + pp;
        if (n < N_POINTS) {
            const u32 w = tile[ll][pp];
            f32x2 e;
            e.x = __half2float(__ushort_as_half((unsigned short)(w & 0xFFFFu)));
            e.y = __half2float(__ushort_as_half((unsigned short)(w >> 16)));
            __builtin_nontemporal_store(e, &out[(size_t)n * NLEV + ll]);
        }
    }
}

// ---- fallback: ws-free direct kernel (round-1, known-pass) -----------------
__global__ __launch_bounds__(256) void hash_enc_direct(
        const float* __restrict__ coords,
        const float* __restrict__ tables,
        float* __restrict__ out) {
    const int tid = blockIdx.x * blockDim.x + threadIdx.x;
    if (tid >= N_POINTS * NLEV) return;
    const int n = tid >> 4;
    const int l = tid & 15;
    const float cx = coords[n*3+0], cy = coords[n*3+1], cz = coords[n*3+2];
    const int flat = part_of(cx, cy, cz);
    float s0, s1;
    enc_core(tables + ((size_t)(flat * NLEV + l)) * TF, c_res[l], cx, cy, cz, s0, s1);
    f32x2 rr; rr.x = s0; rr.y = s1;
    ((f32x2*)out)[tid] = rr;
}

extern "C" void kernel_launch(void* const* d_in, const int* in_sizes, int n_in,
                              void* d_out, int out_size, void* d_ws, size_t ws_size,
                              hipStream_t stream) {
    const float* coords = (const float*)d_in[0];
    const float* tables = (const float*)d_in[1];

    if (ws_size >= WSOUT_F16_BYTES) {
        u32* wsout = (u32*)d_ws;
        enc4_k<<<NLEV * NCH4, 256, 0, stream>>>(coords, tables, wsout);
        transpose_f16_k<<<CHUNKS, 256, 0, stream>>>(wsout, (f32x2*)d_out);
    } else {
        const int total = N_POINTS * NLEV;
        hash_enc_direct<<<(total + 255) / 256, 256, 0, stream>>>(
            coords, tables, (float*)d_out);
    }
}